// Round 2
// baseline (1151.964 us; speedup 1.0000x reference)
//
#include <hip/hip_runtime.h>
#include <cstdint>
#include <cstddef>

typedef __attribute__((ext_vector_type(8))) short bf16x8;   // 8 bf16 in 4 VGPRs
typedef __attribute__((ext_vector_type(4))) float f32x4;

// ---------- helpers ----------
static __device__ __forceinline__ unsigned short f2bf(float f) {
  unsigned int u = __float_as_uint(f);
  u += 0x7fffu + ((u >> 16) & 1u);          // RNE
  return (unsigned short)(u >> 16);
}

static __device__ __forceinline__ void gload16(const unsigned short* g, unsigned short* l) {
  // async global->LDS, 16B per lane; LDS dest = wave-uniform base + lane*16
  __builtin_amdgcn_global_load_lds(
      (const __attribute__((address_space(1))) void*)g,
      (__attribute__((address_space(3))) void*)l, 16, 0, 0);
}

// ---------- ROI max pool -> bf16 A matrix (1024 x 25088) ----------
__global__ __launch_bounds__(256) void roi_pool_k(
    const float* __restrict__ feat, const int* __restrict__ rois,
    unsigned short* __restrict__ Abf)
{
  const int idx = blockIdx.x * 256 + threadIdx.x;   // < 1024*512*49
  const int n   = idx / (512 * 49);
  const int rem = idx - n * (512 * 49);
  const int c   = rem / 49;
  const int p   = rem - c * 49;
  const int oy  = p / 7, ox = p - oy * 7;

  const int* r = rois + n * 5;
  const int b  = r[0];
  const int x1 = r[1] >> 4, y1 = r[2] >> 4;
  const int x2 = (r[3] + 15) >> 4, y2 = (r[4] + 15) >> 4;
  const int h = y2 - y1, w = x2 - x1;
  const int ys = y1 + (oy * h) / 7, ye = y1 + ((oy + 1) * h + 6) / 7;
  const int xs = x1 + (ox * w) / 7, xe = x1 + ((ox + 1) * w + 6) / 7;

  const float* f = feat + (size_t)(b * 512 + c) * 196;
  float m = -3.402823466e38f;
  for (int y = ys; y < ye; ++y)
    for (int x = xs; x < xe; ++x)
      m = fmaxf(m, f[y * 14 + x]);
  Abf[idx] = f2bf(m);   // idx == n*25088 + c*49 + oy*7 + ox
}

// ---------- fp32 (K,N) -> bf16 (N,K) transpose+convert, 64x64 LDS tiles ----------
__global__ __launch_bounds__(256) void transpose_convert_bf16(
    const float* __restrict__ W, unsigned short* __restrict__ WT, int K, int N)
{
  __shared__ float tile[64][65];
  const int t  = threadIdx.x;
  const int k0 = blockIdx.x * 64;
  const int n0 = blockIdx.y * 64;
  const int tr = t >> 4;
  const int tc = (t & 15) * 4;
#pragma unroll
  for (int j = 0; j < 4; ++j) {
    const int kk = j * 16 + tr;
    const f32x4 v = *(const f32x4*)&W[(size_t)(k0 + kk) * N + n0 + tc];
#pragma unroll
    for (int i = 0; i < 4; ++i) tile[kk][tc + i] = v[i];
  }
  __syncthreads();
#pragma unroll
  for (int j = 0; j < 4; ++j) {
    const int nn = j * 16 + tr;
    ushort4 o;
    o.x = f2bf(tile[tc + 0][nn]);
    o.y = f2bf(tile[tc + 1][nn]);
    o.z = f2bf(tile[tc + 2][nn]);
    o.w = f2bf(tile[tc + 3][nn]);
    *(ushort4*)&WT[(size_t)(n0 + nn) * K + k0 + tc] = o;
  }
}

// ---------- concat cls_w | bbox_w -> bf16 (128 x 4096), rows 105..127 zero ----------
__global__ __launch_bounds__(256) void fill_hwt(
    const float* __restrict__ cls_w, const float* __restrict__ bbox_w,
    unsigned short* __restrict__ HWT)
{
  const int idx = blockIdx.x * 256 + threadIdx.x;  // < 128*4096
  const int nn = idx >> 12, k = idx & 4095;
  float v = 0.f;
  if (nn < 21) v = cls_w[k * 21 + nn];
  else if (nn < 105) v = bbox_w[k * 84 + (nn - 21)];
  HWT[idx] = f2bf(v);
}

// ---------- bf16 GEMM: C = A(MxK) * BT(NxK)^T, 128x128 tile, BK=32, split-K ----------
// 4 waves (2x2), each wave 64x64 output (4x4 frags of 16x16x32 MFMA).
// 2-phase LDS double-buffer, global_load_lds width-16 staging.
__global__ __launch_bounds__(256) void gemm_bf16_dbuf(
    const unsigned short* __restrict__ A,
    const unsigned short* __restrict__ BT,
    float* __restrict__ Cp,           // [gridDim.z][M][N] partials
    int ld, int M, int N, int ksteps)
{
  __shared__ unsigned short As[2][128 * 32];
  __shared__ unsigned short Bs[2][128 * 32];
  const int tid  = threadIdx.x;
  const int wave = tid >> 6;
  const int lane = tid & 63;
  const int m0 = blockIdx.y * 128;
  const int n0 = blockIdx.x * 128;
  const long kbeg = (long)blockIdx.z * ksteps * 32;

  // staging: per gload call a wave covers 16 rows x 32 k; lane -> (row, 8k)
  const int srow = lane >> 2;
  const int scol = (lane & 3) << 3;
  const unsigned short* Ag0 = A  + (size_t)(m0 + wave * 16 + srow) * ld + kbeg + scol;
  const unsigned short* Ag1 = Ag0 + (size_t)64 * ld;
  const unsigned short* Bg0 = BT + (size_t)(n0 + wave * 16 + srow) * ld + kbeg + scol;
  const unsigned short* Bg1 = Bg0 + (size_t)64 * ld;

  f32x4 acc[4][4];
  const f32x4 zero = {0.f, 0.f, 0.f, 0.f};
#pragma unroll
  for (int i = 0; i < 4; i++)
#pragma unroll
    for (int j = 0; j < 4; j++) acc[i][j] = zero;

  const int wr = (wave >> 1) * 64;
  const int wc = (wave & 1) * 64;
  const int fr = lane & 15;
  const int fk = (lane >> 4) * 8;

  { // prologue: stage tile 0 into buf 0
    unsigned short* la = &As[0][wave * 512];
    unsigned short* lb = &Bs[0][wave * 512];
    gload16(Ag0, la);
    gload16(Ag1, la + 2048);
    gload16(Bg0, lb);
    gload16(Bg1, lb + 2048);
  }
  __syncthreads();

  for (int t = 0; t < ksteps; ++t) {
    const int cur = t & 1;
    if (t + 1 < ksteps) {            // stage next tile into other buffer
      const size_t ko = (size_t)(t + 1) * 32;
      unsigned short* la = &As[cur ^ 1][wave * 512];
      unsigned short* lb = &Bs[cur ^ 1][wave * 512];
      gload16(Ag0 + ko, la);
      gload16(Ag1 + ko, la + 2048);
      gload16(Bg0 + ko, lb);
      gload16(Bg1 + ko, lb + 2048);
    }
    bf16x8 a[4], b[4];
#pragma unroll
    for (int i = 0; i < 4; i++)
      a[i] = *(const bf16x8*)&As[cur][(wr + i * 16 + fr) * 32 + fk];
#pragma unroll
    for (int j = 0; j < 4; j++)
      b[j] = *(const bf16x8*)&Bs[cur][(wc + j * 16 + fr) * 32 + fk];
#pragma unroll
    for (int i = 0; i < 4; i++)
#pragma unroll
      for (int j = 0; j < 4; j++)
        acc[i][j] = __builtin_amdgcn_mfma_f32_16x16x32_bf16(a[i], b[j], acc[i][j], 0, 0, 0);
    __syncthreads();                 // drains vmcnt(0): next tile landed
  }

  float* Cz = Cp + (size_t)blockIdx.z * M * N;
  const int crow = m0 + wr + (lane >> 4) * 4;
  const int ccol = n0 + wc + fr;
#pragma unroll
  for (int i = 0; i < 4; i++)
#pragma unroll
    for (int j = 0; j < 4; j++)
#pragma unroll
      for (int r = 0; r < 4; r++)
        Cz[(size_t)(crow + i * 16 + r) * N + (ccol + j * 16)] = acc[i][j][r];
}

// ---------- split-K=2 reduce + bias + ReLU -> bf16 ----------
__global__ __launch_bounds__(256) void reduce_bias_relu_bf16(
    const float* __restrict__ Cp, const float* __restrict__ bias,
    unsigned short* __restrict__ Xo, int MN, int N)
{
  const int idx = blockIdx.x * 256 + threadIdx.x;
  const size_t e = (size_t)idx * 4;
  if (e >= (size_t)MN) return;
  const f32x4 v0 = *(const f32x4*)&Cp[e];
  const f32x4 v1 = *(const f32x4*)&Cp[(size_t)MN + e];
  const f32x4 bb = *(const f32x4*)&bias[(int)(e & (size_t)(N - 1))];
  ushort4 o;
  o.x = f2bf(fmaxf(v0[0] + v1[0] + bb[0], 0.f));
  o.y = f2bf(fmaxf(v0[1] + v1[1] + bb[1], 0.f));
  o.z = f2bf(fmaxf(v0[2] + v1[2] + bb[2], 0.f));
  o.w = f2bf(fmaxf(v0[3] + v1[3] + bb[3], 0.f));
  *(ushort4*)&Xo[e] = o;
}

// ---------- head split-K=16 reduce + bias, scatter into cls/bbox output ----------
__global__ __launch_bounds__(256) void head_reduce(
    const float* __restrict__ Hp, const float* __restrict__ cls_b,
    const float* __restrict__ bbox_b, float* __restrict__ out)
{
  const int idx = blockIdx.x * 256 + threadIdx.x;   // < 1024*105
  if (idx >= 1024 * 105) return;
  const int m = idx / 105, nn = idx - m * 105;
  float s = 0.f;
#pragma unroll
  for (int z = 0; z < 16; ++z) s += Hp[((size_t)z * 1024 + m) * 128 + nn];
  if (nn < 21) out[m * 21 + nn] = s + cls_b[nn];
  else out[21504 + m * 84 + (nn - 21)] = s + bbox_b[nn - 21];
}

// ---------- launch ----------
extern "C" void kernel_launch(void* const* d_in, const int* in_sizes, int n_in,
                              void* d_out, int out_size, void* d_ws, size_t ws_size,
                              hipStream_t stream)
{
  const float* feat   = (const float*)d_in[0];
  const int*   rois   = (const int*)d_in[1];
  const float* fc1_w  = (const float*)d_in[2];
  const float* fc1_b  = (const float*)d_in[3];
  const float* fc2_w  = (const float*)d_in[4];
  const float* fc2_b  = (const float*)d_in[5];
  const float* cls_w  = (const float*)d_in[6];
  const float* cls_b  = (const float*)d_in[7];
  const float* bbox_w = (const float*)d_in[8];
  const float* bbox_b = (const float*)d_in[9];
  float* out = (float*)d_out;

  char* ws = (char*)d_ws;
  const size_t A_OFF   = 0;                         // 1024*25088*2  = 51,380,224
  const size_t W1T_OFF = 51380224;                  // 4096*25088*2 = 205,520,896
  const size_t W2T_OFF = 256901120;                 // 4096*4096*2  =  33,554,432
  const size_t HWT_OFF = 290455552;                 // 128*4096*2   =   1,048,576
  const size_t P_OFF   = 291504128;                 // partials     =  33,554,432 (reused 3x)
  const size_t X_OFF   = 325058560;                 // 1024*4096*2  =   8,388,608
  const size_t F_OFF   = 333447168;                 // 1024*4096*2  =   8,388,608
  const size_t NEED    = 341835776;
  if (ws_size < NEED) {                             // visible diagnostic, no crash
    hipMemsetAsync(d_out, 0, (size_t)out_size * 4, stream);
    return;
  }

  unsigned short* Abf = (unsigned short*)(ws + A_OFF);
  unsigned short* W1T = (unsigned short*)(ws + W1T_OFF);
  unsigned short* W2T = (unsigned short*)(ws + W2T_OFF);
  unsigned short* HWT = (unsigned short*)(ws + HWT_OFF);
  float*          P   = (float*)(ws + P_OFF);
  unsigned short* X   = (unsigned short*)(ws + X_OFF);
  unsigned short* F   = (unsigned short*)(ws + F_OFF);

  // weight prep
  transpose_convert_bf16<<<dim3(392, 64), 256, 0, stream>>>(fc1_w, W1T, 25088, 4096);
  transpose_convert_bf16<<<dim3(64, 64),  256, 0, stream>>>(fc2_w, W2T, 4096, 4096);
  fill_hwt<<<2048, 256, 0, stream>>>(cls_w, bbox_w, HWT);

  // roi pool -> A (bf16)
  roi_pool_k<<<100352, 256, 0, stream>>>(feat, rois, Abf);

  // fc1: (1024x25088)x(25088x4096), split-K=2 -> 512 blocks
  gemm_bf16_dbuf<<<dim3(32, 8, 2), 256, 0, stream>>>(Abf, W1T, P, 25088, 1024, 4096, 392);
  reduce_bias_relu_bf16<<<4096, 256, 0, stream>>>(P, fc1_b, X, 1024 * 4096, 4096);

  // fc2: (1024x4096)x(4096x4096), split-K=2
  gemm_bf16_dbuf<<<dim3(32, 8, 2), 256, 0, stream>>>(X, W2T, P, 4096, 1024, 4096, 64);
  reduce_bias_relu_bf16<<<4096, 256, 0, stream>>>(P, fc2_b, F, 1024 * 4096, 4096);

  // heads: (1024x4096)x(4096x128pad), split-K=16
  gemm_bf16_dbuf<<<dim3(1, 8, 16), 256, 0, stream>>>(F, HWT, P, 4096, 1024, 128, 8);
  head_reduce<<<420, 256, 0, stream>>>(P, cls_b, bbox_b, out);
}

// Round 3
// 1093.069 us; speedup vs baseline: 1.0539x; 1.0539x over previous
//
#include <hip/hip_runtime.h>
#include <cstdint>
#include <cstddef>

typedef __attribute__((ext_vector_type(8))) short bf16x8;   // 8 bf16 in 4 VGPRs
typedef __attribute__((ext_vector_type(4))) float f32x4;

// ---------- helpers ----------
static __device__ __forceinline__ unsigned short f2bf(float f) {
  unsigned int u = __float_as_uint(f);
  u += 0x7fffu + ((u >> 16) & 1u);          // RNE
  return (unsigned short)(u >> 16);
}

static __device__ __forceinline__ void gload16(const unsigned short* g, unsigned short* l) {
  // async global->LDS, 16B per lane; LDS dest = wave-uniform base + lane*16
  __builtin_amdgcn_global_load_lds(
      (const __attribute__((address_space(1))) void*)g,
      (__attribute__((address_space(3))) void*)l, 16, 0, 0);
}

// ---------- ROI max pool -> bf16 A matrix (1024 x 25088) ----------
__global__ __launch_bounds__(256) void roi_pool_k(
    const float* __restrict__ feat, const int* __restrict__ rois,
    unsigned short* __restrict__ Abf)
{
  const int idx = blockIdx.x * 256 + threadIdx.x;   // < 1024*512*49
  const int n   = idx / (512 * 49);
  const int rem = idx - n * (512 * 49);
  const int c   = rem / 49;
  const int p   = rem - c * 49;
  const int oy  = p / 7, ox = p - oy * 7;

  const int* r = rois + n * 5;
  const int b  = r[0];
  const int x1 = r[1] >> 4, y1 = r[2] >> 4;
  const int x2 = (r[3] + 15) >> 4, y2 = (r[4] + 15) >> 4;
  const int h = y2 - y1, w = x2 - x1;
  const int ys = y1 + (oy * h) / 7, ye = y1 + ((oy + 1) * h + 6) / 7;
  const int xs = x1 + (ox * w) / 7, xe = x1 + ((ox + 1) * w + 6) / 7;

  const float* f = feat + (size_t)(b * 512 + c) * 196;
  float m = -3.402823466e38f;
  for (int y = ys; y < ye; ++y)
    for (int x = xs; x < xe; ++x)
      m = fmaxf(m, f[y * 14 + x]);
  Abf[idx] = f2bf(m);   // idx == n*25088 + c*49 + oy*7 + ox
}

// ---------- fp32 (K,N) -> bf16 (N,K) transpose+convert, 64x64 LDS tiles ----------
__global__ __launch_bounds__(256) void transpose_convert_bf16(
    const float* __restrict__ W, unsigned short* __restrict__ WT, int K, int N)
{
  __shared__ float tile[64][68];   // pad 68: 16B-aligned rows -> vector ds_write
  const int t  = threadIdx.x;
  const int k0 = blockIdx.x * 64;
  const int n0 = blockIdx.y * 64;
  const int tr = t >> 4;
  const int tc = (t & 15) * 4;
#pragma unroll
  for (int j = 0; j < 4; ++j) {
    const int kk = j * 16 + tr;
    const f32x4 v = *(const f32x4*)&W[(size_t)(k0 + kk) * N + n0 + tc];
    *(f32x4*)&tile[kk][tc] = v;    // (kk*68+tc)*4 is 16B-aligned
  }
  __syncthreads();
#pragma unroll
  for (int j = 0; j < 4; ++j) {
    const int nn = j * 16 + tr;
    ushort4 o;
    o.x = f2bf(tile[tc + 0][nn]);
    o.y = f2bf(tile[tc + 1][nn]);
    o.z = f2bf(tile[tc + 2][nn]);
    o.w = f2bf(tile[tc + 3][nn]);
    *(ushort4*)&WT[(size_t)(n0 + nn) * K + k0 + tc] = o;
  }
}

// ---------- concat cls_w | bbox_w -> bf16 (128 x 4096), rows 105..127 zero ----------
__global__ __launch_bounds__(256) void fill_hwt(
    const float* __restrict__ cls_w, const float* __restrict__ bbox_w,
    unsigned short* __restrict__ HWT)
{
  const int idx = blockIdx.x * 256 + threadIdx.x;  // < 128*4096
  const int nn = idx >> 12, k = idx & 4095;
  float v = 0.f;
  if (nn < 21) v = cls_w[k * 21 + nn];
  else if (nn < 105) v = bbox_w[k * 84 + (nn - 21)];
  HWT[idx] = f2bf(v);
}

// ---------- bf16 GEMM: C = A(MxK) * BT(NxK)^T, 128x128 tile, BK=32, split-K ----------
// 4 waves (2x2), each wave 64x64 output (4x4 frags of 16x16x32 MFMA).
// 2-phase LDS double-buffer, global_load_lds width-16 staging.
__global__ __launch_bounds__(256) void gemm_bf16_dbuf(
    const unsigned short* __restrict__ A,
    const unsigned short* __restrict__ BT,
    float* __restrict__ Cp,           // [gridDim.z][M][N] partials
    int ld, int M, int N, int ksteps)
{
  __shared__ unsigned short As[2][128 * 32];
  __shared__ unsigned short Bs[2][128 * 32];
  const int tid  = threadIdx.x;
  const int wave = tid >> 6;
  const int lane = tid & 63;
  const int m0 = blockIdx.y * 128;
  const int n0 = blockIdx.x * 128;
  const long kbeg = (long)blockIdx.z * ksteps * 32;

  // staging: per gload call a wave covers 16 rows x 32 k; lane -> (row, 8k)
  const int srow = lane >> 2;
  const int scol = (lane & 3) << 3;
  const unsigned short* Ag0 = A  + (size_t)(m0 + wave * 16 + srow) * ld + kbeg + scol;
  const unsigned short* Ag1 = Ag0 + (size_t)64 * ld;
  const unsigned short* Bg0 = BT + (size_t)(n0 + wave * 16 + srow) * ld + kbeg + scol;
  const unsigned short* Bg1 = Bg0 + (size_t)64 * ld;

  f32x4 acc[4][4];
  const f32x4 zero = {0.f, 0.f, 0.f, 0.f};
#pragma unroll
  for (int i = 0; i < 4; i++)
#pragma unroll
    for (int j = 0; j < 4; j++) acc[i][j] = zero;

  const int wr = (wave >> 1) * 64;
  const int wc = (wave & 1) * 64;
  const int fr = lane & 15;
  const int fk = (lane >> 4) * 8;

  { // prologue: stage tile 0 into buf 0
    unsigned short* la = &As[0][wave * 512];
    unsigned short* lb = &Bs[0][wave * 512];
    gload16(Ag0, la);
    gload16(Ag1, la + 2048);
    gload16(Bg0, lb);
    gload16(Bg1, lb + 2048);
  }
  __syncthreads();

  for (int t = 0; t < ksteps; ++t) {
    const int cur = t & 1;
    if (t + 1 < ksteps) {            // stage next tile into other buffer
      const size_t ko = (size_t)(t + 1) * 32;
      unsigned short* la = &As[cur ^ 1][wave * 512];
      unsigned short* lb = &Bs[cur ^ 1][wave * 512];
      gload16(Ag0 + ko, la);
      gload16(Ag1 + ko, la + 2048);
      gload16(Bg0 + ko, lb);
      gload16(Bg1 + ko, lb + 2048);
    }
    bf16x8 a[4], b[4];
#pragma unroll
    for (int i = 0; i < 4; i++)
      a[i] = *(const bf16x8*)&As[cur][(wr + i * 16 + fr) * 32 + fk];
#pragma unroll
    for (int j = 0; j < 4; j++)
      b[j] = *(const bf16x8*)&Bs[cur][(wc + j * 16 + fr) * 32 + fk];
#pragma unroll
    for (int i = 0; i < 4; i++)
#pragma unroll
      for (int j = 0; j < 4; j++)
        acc[i][j] = __builtin_amdgcn_mfma_f32_16x16x32_bf16(a[i], b[j], acc[i][j], 0, 0, 0);
    __syncthreads();                 // drains vmcnt(0): next tile landed
  }

  float* Cz = Cp + (size_t)blockIdx.z * M * N;
  const int crow = m0 + wr + (lane >> 4) * 4;
  const int ccol = n0 + wc + fr;
#pragma unroll
  for (int i = 0; i < 4; i++)
#pragma unroll
    for (int j = 0; j < 4; j++)
#pragma unroll
      for (int r = 0; r < 4; r++)
        Cz[(size_t)(crow + i * 16 + r) * N + (ccol + j * 16)] = acc[i][j][r];
}

// ---------- split-K reduce + bias + ReLU -> bf16 (z partials) ----------
__global__ __launch_bounds__(256) void reduce_bias_relu_bf16(
    const float* __restrict__ Cp, const float* __restrict__ bias,
    unsigned short* __restrict__ Xo, int MN, int N, int KZ)
{
  const int idx = blockIdx.x * 256 + threadIdx.x;
  const size_t e = (size_t)idx * 4;
  if (e >= (size_t)MN) return;
  f32x4 s = *(const f32x4*)&Cp[e];
  for (int z = 1; z < KZ; ++z) {
    const f32x4 v = *(const f32x4*)&Cp[(size_t)z * MN + e];
    s[0] += v[0]; s[1] += v[1]; s[2] += v[2]; s[3] += v[3];
  }
  const f32x4 bb = *(const f32x4*)&bias[(int)(e & (size_t)(N - 1))];
  ushort4 o;
  o.x = f2bf(fmaxf(s[0] + bb[0], 0.f));
  o.y = f2bf(fmaxf(s[1] + bb[1], 0.f));
  o.z = f2bf(fmaxf(s[2] + bb[2], 0.f));
  o.w = f2bf(fmaxf(s[3] + bb[3], 0.f));
  *(ushort4*)&Xo[e] = o;
}

// ---------- head split-K=16 reduce + bias, scatter into cls/bbox output ----------
__global__ __launch_bounds__(256) void head_reduce(
    const float* __restrict__ Hp, const float* __restrict__ cls_b,
    const float* __restrict__ bbox_b, float* __restrict__ out)
{
  const int idx = blockIdx.x * 256 + threadIdx.x;   // < 1024*105
  if (idx >= 1024 * 105) return;
  const int m = idx / 105, nn = idx - m * 105;
  float s = 0.f;
#pragma unroll
  for (int z = 0; z < 16; ++z) s += Hp[((size_t)z * 1024 + m) * 128 + nn];
  if (nn < 21) out[m * 21 + nn] = s + cls_b[nn];
  else out[21504 + m * 84 + (nn - 21)] = s + bbox_b[nn - 21];
}

// ---------- launch ----------
extern "C" void kernel_launch(void* const* d_in, const int* in_sizes, int n_in,
                              void* d_out, int out_size, void* d_ws, size_t ws_size,
                              hipStream_t stream)
{
  const float* feat   = (const float*)d_in[0];
  const int*   rois   = (const int*)d_in[1];
  const float* fc1_w  = (const float*)d_in[2];
  const float* fc1_b  = (const float*)d_in[3];
  const float* fc2_w  = (const float*)d_in[4];
  const float* fc2_b  = (const float*)d_in[5];
  const float* cls_w  = (const float*)d_in[6];
  const float* cls_b  = (const float*)d_in[7];
  const float* bbox_w = (const float*)d_in[8];
  const float* bbox_b = (const float*)d_in[9];
  float* out = (float*)d_out;

  char* ws = (char*)d_ws;
  // A:[0,51.4M) W1T:[51.4,256.9M) W2T:[256.9,290.5M) HWT:[290.5,291.5M) P:[291.5M, +KZ*16.8M)
  // X/F reuse the A region (A is dead after the FC1 GEMM completes).
  const size_t A_OFF   = 0;
  const size_t W1T_OFF = 51380224;
  const size_t W2T_OFF = 256901120;
  const size_t HWT_OFF = 290455552;
  const size_t P_OFF   = 291504128;
  const size_t PZ      = 67108864 / 4;              // 16,777,216 bytes per z-slice
  const size_t NEED4   = P_OFF + 4 * PZ;            // 358,612,992
  const size_t NEED2   = P_OFF + 2 * PZ;            // 325,058,560
  int KZ;
  if (ws_size >= NEED4)      KZ = 4;
  else if (ws_size >= NEED2) KZ = 2;
  else {                                            // visible diagnostic, no crash
    hipMemsetAsync(d_out, 0, (size_t)out_size * 4, stream);
    return;
  }

  unsigned short* Abf = (unsigned short*)(ws + A_OFF);
  unsigned short* W1T = (unsigned short*)(ws + W1T_OFF);
  unsigned short* W2T = (unsigned short*)(ws + W2T_OFF);
  unsigned short* HWT = (unsigned short*)(ws + HWT_OFF);
  float*          P   = (float*)(ws + P_OFF);
  unsigned short* X   = (unsigned short*)(ws + 0);         // A region, reused
  unsigned short* F   = (unsigned short*)(ws + 8388608);   // A region, reused

  // weight prep
  transpose_convert_bf16<<<dim3(392, 64), 256, 0, stream>>>(fc1_w, W1T, 25088, 4096);
  transpose_convert_bf16<<<dim3(64, 64),  256, 0, stream>>>(fc2_w, W2T, 4096, 4096);
  fill_hwt<<<2048, 256, 0, stream>>>(cls_w, bbox_w, HWT);

  // roi pool -> A (bf16)
  roi_pool_k<<<100352, 256, 0, stream>>>(feat, rois, Abf);

  // fc1: (1024x25088)x(25088x4096), split-K=KZ -> KZ*256 blocks (4 blocks/CU at KZ=4)
  gemm_bf16_dbuf<<<dim3(32, 8, KZ), 256, 0, stream>>>(Abf, W1T, P, 25088, 1024, 4096, 784 / KZ);
  reduce_bias_relu_bf16<<<4096, 256, 0, stream>>>(P, fc1_b, X, 1024 * 4096, 4096, KZ);

  // fc2: (1024x4096)x(4096x4096), split-K=KZ
  gemm_bf16_dbuf<<<dim3(32, 8, KZ), 256, 0, stream>>>(X, W2T, P, 4096, 1024, 4096, 128 / KZ);
  reduce_bias_relu_bf16<<<4096, 256, 0, stream>>>(P, fc2_b, F, 1024 * 4096, 4096, KZ);

  // heads: (1024x4096)x(4096x128pad), split-K=16
  gemm_bf16_dbuf<<<dim3(1, 8, 16), 256, 0, stream>>>(F, HWT, P, 4096, 1024, 128, 8);
  head_reduce<<<420, 256, 0, stream>>>(P, cls_b, bbox_b, out);
}